// Round 7
// baseline (270.898 us; speedup 1.0000x reference)
//
#include <hip/hip_runtime.h>

typedef __bf16 bf16;
typedef __bf16 bf16x4 __attribute__((ext_vector_type(4)));
typedef __bf16 bf16x8 __attribute__((ext_vector_type(8)));
typedef float f32x4 __attribute__((ext_vector_type(4)));

#define AS1C(p) ((const __attribute__((address_space(1))) void*)(p))
#define AS3(p)  ((__attribute__((address_space(3))) void*)(p))

#define T_SEQ 2048
#define QK_LD 2048

extern "C" __device__ float __ocml_native_exp2_f32(float);   // raw v_exp_f32

// ---------------------------------------------------------------------------
// Prep kernels
// ---------------------------------------------------------------------------
__global__ void cvt_f32_bf16(const float* __restrict__ X, bf16* __restrict__ Y, int n) {
    int i = (blockIdx.x * 256 + threadIdx.x) * 4;
    if (i >= n) return;
    const float4 f = *(const float4*)(X + i);
    bf16x4 o;
    o.x = (bf16)f.x; o.y = (bf16)f.y; o.z = (bf16)f.z; o.w = (bf16)f.w;
    *(bf16x4*)(Y + i) = o;
}

// W[R][C] fp32 (row-major) -> Wt[C][R] bf16
__global__ void transpose_cvt(const float* __restrict__ W, bf16* __restrict__ Wt,
                              int R, int C) {
    __shared__ float tile[32][33];
    const int bx = blockIdx.x * 32;
    const int by = blockIdx.y * 32;
    const int tx = threadIdx.x, ty = threadIdx.y;
#pragma unroll
    for (int i = 0; i < 32; i += 8)
        tile[ty + i][tx] = W[(size_t)(by + ty + i) * C + bx + tx];
    __syncthreads();
#pragma unroll
    for (int i = 0; i < 32; i += 8)
        Wt[(size_t)(bx + ty + i) * R + by + tx] = (bf16)tile[tx][ty + i];
}

// ---------------------------------------------------------------------------
// GEMM: C[M,N] = A[M,K]*Bt[N,K]^T (+bias). bf16 in, fp32 acc.
// LDS-BW-bound fix: 256x128 block tile, wave tile 64x128 -> 12 ds_read_b128
// feed 32 MFMA (0.375 reads/MFMA vs 0.5 at 64x64). DS per phase = 72 KB for
// 2x FLOPs of the old 48 KB -> DS:MFMA 2.47 -> 1.81.
// global_load_lds staging (no staging VGPRs; acc needs 128), dbuf 48 KB LDS,
// XOR chunk swizzle: chunk(row,kb) at slot kb^((row>>1)&3).
// ---------------------------------------------------------------------------
template <bool OUT_BF16, bool SPLIT_V>
__global__ __launch_bounds__(256, 2)
void gemm_bt(const bf16* __restrict__ A, const bf16* __restrict__ Bt,
             const float* __restrict__ bias, void* __restrict__ Cout,
             bf16* __restrict__ Vtb, int M, int N, int K, int ldC) {
    __shared__ bf16 sm[24576];   // 2 bufs x (A 8192 + B 4096 elems) = 48 KB

    const int t = threadIdx.x;
    const int lane = t & 63, quad = lane >> 4, l16 = lane & 15;
    const int wave = t >> 6;
    const int wm = wave * 64;                 // wave's M rows (wave tile 64x128)
    const long m0 = (long)blockIdx.y * 256;
    const long n0 = (long)blockIdx.x * 128;

    f32x4 acc[4][8] = {};                     // [i m-tile][j n-tile]

    // staging: A 1024 chunks (4/thread), B 512 chunks (2/thread)
    const int sr = t >> 2, sc = t & 3;        // row-in-64 group, slot
    const int skb = sc ^ ((sr >> 1) & 3);     // logical chunk for this slot
    const bf16* agp = A  + (m0 + sr) * (long)K + skb * 8;
    const bf16* bgp = Bt + (n0 + sr) * (long)K + skb * 8;
    const long rowK = (long)64 * K;

    // frag read offsets (elems, loop-invariant)
    int offA[4], offB[8];
#pragma unroll
    for (int i = 0; i < 4; ++i) {
        const int row = wm + i * 16 + l16;
        offA[i] = (row * 4 + (quad ^ ((row >> 1) & 3))) * 8;
    }
#pragma unroll
    for (int j = 0; j < 8; ++j) {
        const int row = j * 16 + l16;
        offB[j] = 8192 + (row * 4 + (quad ^ ((row >> 1) & 3))) * 8;
    }

    auto stage = [&](int buf, int k0) {
        bf16* base = &sm[buf * 12288];
#pragma unroll
        for (int i = 0; i < 4; ++i)
            __builtin_amdgcn_global_load_lds(AS1C(agp + i * rowK + k0),
                                             AS3(base + i * 2048 + t * 8), 16, 0, 0);
#pragma unroll
        for (int i = 0; i < 2; ++i)
            __builtin_amdgcn_global_load_lds(AS1C(bgp + i * rowK + k0),
                                             AS3(base + 8192 + i * 2048 + t * 8), 16, 0, 0);
    };
    auto compute = [&](int buf) {
        const bf16* s = &sm[buf * 12288];
        bf16x8 af[4], bfr[8];
#pragma unroll
        for (int i = 0; i < 4; ++i) af[i] = *(const bf16x8*)(s + offA[i]);
#pragma unroll
        for (int j = 0; j < 8; ++j) bfr[j] = *(const bf16x8*)(s + offB[j]);
#pragma unroll
        for (int i = 0; i < 4; ++i)
#pragma unroll
            for (int j = 0; j < 8; ++j)   // swapped: D row=n, col=m
                acc[i][j] = __builtin_amdgcn_mfma_f32_16x16x32_bf16(bfr[j], af[i], acc[i][j], 0, 0, 0);
    };

    const int nk = K >> 5;   // BK=32 phases (even)
    stage(0, 0);
    for (int kk = 0; kk < nk; kk += 2) {
        __syncthreads();                          // buf0 staged (vmcnt drained)
        if (kk + 1 < nk) stage(1, (kk + 1) * 32); // overlaps compute(0)
        compute(0);
        __syncthreads();                          // buf1 staged
        if (kk + 2 < nk) stage(0, (kk + 2) * 32);
        compute(1);
    }

    // epilogue: lane holds m = m0+wm+i*16+l16, n = n0+j*16+quad*4+r
    bf16*  Cb = (bf16*)Cout;
    float* Cf = (float*)Cout;
    const bool vblock = SPLIT_V && (n0 >= 2048);
#pragma unroll
    for (int i = 0; i < 4; ++i) {
        const long gm = m0 + wm + i * 16 + l16;
#pragma unroll
        for (int j = 0; j < 8; ++j) {
            const long n = n0 + j * 16 + quad * 4;
            const float4 bv = *(const float4*)(bias + n);
            float v[4];
#pragma unroll
            for (int r = 0; r < 4; ++r) v[r] = acc[i][j][r] + (&bv.x)[r];
            if (vblock) {
                const int bb = (int)(gm >> 11), tok = (int)(gm & 2047);
                const int nv = (int)(n - 2048);
                const int h = nv >> 6, d0 = nv & 63;
                bf16* dst = Vtb + ((size_t)(bb * 16 + h) * 64 + d0) * T_SEQ + tok;
#pragma unroll
                for (int r = 0; r < 4; ++r) dst[(size_t)r * T_SEQ] = (bf16)v[r];
            } else if (OUT_BF16) {
                bf16x4 o;
#pragma unroll
                for (int r = 0; r < 4; ++r) o[r] = (bf16)v[r];
                *(bf16x4*)(Cb + gm * ldC + n) = o;
            } else {
                float4 o;
#pragma unroll
                for (int r = 0; r < 4; ++r) (&o.x)[r] = v[r];
                *(float4*)(Cf + gm * ldC + n) = o;
            }
        }
    }
}

// ---------------------------------------------------------------------------
// Causal flash attention, q-tile 256 (wave q-tile 64): K/V frag reads per
// wave now serve 64 q-rows (DS bytes per q-row ~halved vs q-tile 128).
// Fully-masked k-tiles skipped per wave (staging+barriers still executed).
// Transposed orientation + fixed-max exp2 softmax (validated r2-r6).
// ---------------------------------------------------------------------------
__global__ __launch_bounds__(256, 2)
void attn_kernel(const bf16* __restrict__ qk, const bf16* __restrict__ vtb,
                 bf16* __restrict__ Out) {
    const int bh = blockIdx.x;
    const int qt = 7 - (int)blockIdx.y;     // heavy tiles first
    const int b = bh >> 4, h = bh & 15;
    const int t = threadIdx.x;
    const int wave = t >> 6, lane = t & 63, quad = lane >> 4, l16 = lane & 15;
    const int wq = wave * 64;
    const int q0 = qt * 256;

    __shared__ bf16 Ks[2][4096];    // [key 64][dh chunk 8] swizzled, x2
    __shared__ bf16 VTs[2][4096];   // [d 64][key chunk 8] swizzled, x2
    __shared__ bf16 Ps[16384];      // [q 256][key chunk 8] swizzled; stages Q first

    const bf16* Qg = qk + (size_t)b * T_SEQ * QK_LD + h * 64;
    const bf16* Kg = Qg + 1024;
    const bf16* vth = vtb + (size_t)bh * 64 * T_SEQ;

    // ---- stage Q tile [256][64] into Ps (swizzled) ----
    for (int c = t; c < 2048; c += 256) {
        const int row = c >> 3, kb = c & 7;
        *(uint4*)(Ps + row * 64 + ((kb ^ (row & 7)) << 3)) =
            *(const uint4*)(Qg + (size_t)(q0 + row) * QK_LD + kb * 8);
    }
    __syncthreads();
    const float qsc = 0.125f * 1.4426950408889634f;
    bf16x8 qf[4][2];
#pragma unroll
    for (int jt = 0; jt < 4; ++jt)
#pragma unroll
        for (int s = 0; s < 2; ++s) {
            const int row = wq + jt * 16 + l16;
            bf16x8 v = *(const bf16x8*)(Ps + row * 64 + (((s * 4 + quad) ^ (row & 7)) << 3));
#pragma unroll
            for (int e = 0; e < 8; ++e) v[e] = (bf16)((float)v[e] * qsc);
            qf[jt][s] = v;
        }

    // staging: thread t -> rows sr, sr+32; slot t&7 holds logical chunk skb
    const int sr = t >> 3;
    const int skb = (t & 7) ^ (sr & 7);
    const bf16* kp0 = Kg + (size_t)sr * QK_LD + skb * 8;
    const bf16* kp1 = kp0 + (size_t)32 * QK_LD;
    const bf16* vp0 = vth + (size_t)sr * T_SEQ + skb * 8;
    const bf16* vp1 = vp0 + (size_t)32 * T_SEQ;

    int offKV[4][2];
#pragma unroll
    for (int it = 0; it < 4; ++it)
#pragma unroll
        for (int s = 0; s < 2; ++s) {
            const int row = it * 16 + l16;
            offKV[it][s] = row * 64 + (((s * 4 + quad) ^ (row & 7)) << 3);
        }

    f32x4 oacc[4][4] = {};                // [it2 d-tile][jt q-tile]
    float lsum[4] = {0.f, 0.f, 0.f, 0.f};
    const int nkt = (qt + 1) * 4;

    uint4 kr0 = *(const uint4*)kp0, kr1 = *(const uint4*)kp1;
    uint4 vr0 = *(const uint4*)vp0, vr1 = *(const uint4*)vp1;

    for (int kt = 0; kt < nkt; ++kt) {
        const int k0 = kt * 64;
        bf16* kb_ = Ks[kt & 1];
        bf16* vb_ = VTs[kt & 1];
        *(uint4*)(kb_ + t * 8)        = kr0;
        *(uint4*)(kb_ + 2048 + t * 8) = kr1;
        *(uint4*)(vb_ + t * 8)        = vr0;
        *(uint4*)(vb_ + 2048 + t * 8) = vr1;
        __syncthreads();   // publishes kt, retires kt-1 readers

        if (kt + 1 < nkt) {
            const int kn = k0 + 64;
            kr0 = *(const uint4*)(kp0 + (size_t)kn * QK_LD);
            kr1 = *(const uint4*)(kp1 + (size_t)kn * QK_LD);
            vr0 = *(const uint4*)(vp0 + kn);
            vr1 = *(const uint4*)(vp1 + kn);
        }

        // wave-uniform skip of fully-masked tiles (k0 > max qrow of wave)
        if (k0 > q0 + wq + 63) continue;   // barriers already passed this iter

        // ---- S^T = K Q^T ----
        f32x4 sacc[4][4] = {};
#pragma unroll
        for (int s = 0; s < 2; ++s) {
            bf16x8 kf[4];
#pragma unroll
            for (int it = 0; it < 4; ++it)
                kf[it] = *(const bf16x8*)(kb_ + offKV[it][s]);
#pragma unroll
            for (int it = 0; it < 4; ++it)
#pragma unroll
                for (int jt = 0; jt < 4; ++jt)
                    sacc[it][jt] = __builtin_amdgcn_mfma_f32_16x16x32_bf16(kf[it], qf[jt][s], sacc[it][jt], 0, 0, 0);
        }

        // ---- p = exp2(s); lane-local l; swizzled b64 P-writes ----
        const bool need_mask = (k0 + 63 > q0 + wq);
#pragma unroll
        for (int it = 0; it < 4; ++it)
#pragma unroll
            for (int jt = 0; jt < 4; ++jt) {
                const int prow = wq + jt * 16 + l16;
                bf16x4 pb;
                if (need_mask) {
                    const int qrow = q0 + prow;
                    const int kbase = k0 + it * 16 + quad * 4;
#pragma unroll
                    for (int r = 0; r < 4; ++r) {
                        const float e = __ocml_native_exp2_f32(sacc[it][jt][r]);
                        const float p = (kbase + r > qrow) ? 0.f : e;
                        lsum[jt] += p;
                        pb[r] = (bf16)p;
                    }
                } else {
#pragma unroll
                    for (int r = 0; r < 4; ++r) {
                        const float p = __ocml_native_exp2_f32(sacc[it][jt][r]);
                        lsum[jt] += p;
                        pb[r] = (bf16)p;
                    }
                }
                *(bf16x4*)(Ps + prow * 64 +
                           (((it * 2 + (quad >> 1)) ^ (prow & 7)) << 3) + ((quad & 1) << 2)) = pb;
            }

        // ---- O^T += V^T P (wave-private Ps rows) ----
#pragma unroll
        for (int s2 = 0; s2 < 2; ++s2) {
            bf16x8 vf[4], pf[4];
#pragma unroll
            for (int it2 = 0; it2 < 4; ++it2)
                vf[it2] = *(const bf16x8*)(vb_ + offKV[it2][s2]);
#pragma unroll
            for (int jt = 0; jt < 4; ++jt) {
                const int prow = wq + jt * 16 + l16;
                pf[jt] = *(const bf16x8*)(Ps + prow * 64 + (((s2 * 4 + quad) ^ (prow & 7)) << 3));
            }
#pragma unroll
            for (int it2 = 0; it2 < 4; ++it2)
#pragma unroll
                for (int jt = 0; jt < 4; ++jt)
                    oacc[it2][jt] = __builtin_amdgcn_mfma_f32_16x16x32_bf16(vf[it2], pf[jt], oacc[it2][jt], 0, 0, 0);
        }
    }

    float inv[4];
#pragma unroll
    for (int jt = 0; jt < 4; ++jt) {
        float l = lsum[jt];
        l += __shfl_xor(l, 16);
        l += __shfl_xor(l, 32);
        inv[jt] = 1.0f / l;
    }
#pragma unroll
    for (int it2 = 0; it2 < 4; ++it2)
#pragma unroll
        for (int jt = 0; jt < 4; ++jt) {
            bf16x4 ob;
#pragma unroll
            for (int r = 0; r < 4; ++r) ob[r] = (bf16)(oacc[it2][jt][r] * inv[jt]);
            const int qrow = q0 + wq + jt * 16 + l16;
            const int dcol = h * 64 + it2 * 16 + quad * 4;
            *(bf16x4*)&Out[(size_t)(b * T_SEQ + qrow) * 1024 + dcol] = ob;
        }
}

// ---------------------------------------------------------------------------
extern "C" void kernel_launch(void* const* d_in, const int* in_sizes, int n_in,
                              void* d_out, int out_size, void* d_ws, size_t ws_size,
                              hipStream_t stream) {
    const float* x     = (const float*)d_in[0];
    const float* W_qkv = (const float*)d_in[1];
    const float* b_qkv = (const float*)d_in[2];
    const float* W_out = (const float*)d_in[3];
    const float* b_out = (const float*)d_in[4];
    float* out = (float*)d_out;

    char* ws = (char*)d_ws;
    bf16* xb   = (bf16*)ws; ws += (size_t)8192 * 1024 * 2;
    bf16* wtq  = (bf16*)ws; ws += (size_t)3072 * 1024 * 2;
    bf16* wto  = (bf16*)ws; ws += (size_t)1024 * 1024 * 2;
    bf16* qkb  = (bf16*)ws; ws += (size_t)8192 * 2048 * 2;    // Q|K rows
    bf16* vtb  = (bf16*)ws; ws += (size_t)64 * 64 * 2048 * 2; // V^T per bh
    bf16* aout = (bf16*)ws; ws += (size_t)8192 * 1024 * 2;

    cvt_f32_bf16<<<8192, 256, 0, stream>>>(x, xb, 8192 * 1024);
    transpose_cvt<<<dim3(96, 32), dim3(32, 8), 0, stream>>>(W_qkv, wtq, 1024, 3072);
    transpose_cvt<<<dim3(32, 32), dim3(32, 8), 0, stream>>>(W_out, wto, 1024, 1024);

    gemm_bt<true, true><<<dim3(24, 32), 256, 0, stream>>>(
        xb, wtq, b_qkv, (void*)qkb, vtb, 8192, 3072, 1024, 2048);
    attn_kernel<<<dim3(64, 8), 256, 0, stream>>>(qkb, vtb, aout);
    gemm_bt<false, false><<<dim3(8, 32), 256, 0, stream>>>(
        aout, wto, b_out, (void*)out, nullptr, 8192, 1024, 1024, 1024);
}